// Round 18
// baseline (1609.863 us; speedup 1.0000x reference)
//
#include <hip/hip_runtime.h>
#include <math.h>

#define D_DIM 2048
#define T_N   245
#define TOPK  8
#define BM    64
#define NCH   32              // 2048 / 64

typedef __attribute__((ext_vector_type(8))) __bf16 bf16x8;
typedef __attribute__((ext_vector_type(4))) float  f32x4;

// ws layout (~2.4 MB):
//   [0]        : unsigned counter
//   [256]      : token list, unsigned[32768] (128 KB)
//   [256K]     : wtp packed fragments, bf16 [32][16][2][2][64][8]  (2 MB)
#define WS_LIST_OFF   256
#define WS_WTP_OFF    (256 * 1024)

// packed strides (bf16 units)
#define P_C    32768          // 16*2*2*64*8
#define P_FCG  2048           // 2*2*64*8
#define P_KS   1024           // 2*64*8
#define P_HL   512            // 64*8

__device__ __forceinline__ unsigned short bf16_rne(float f) {
    unsigned u = __builtin_bit_cast(unsigned, f);
    u += 0x7FFFu + ((u >> 16) & 1u);
    return (unsigned short)(u >> 16);
}
__device__ __forceinline__ float bf16_to_f(unsigned short h) {
    return __builtin_bit_cast(float, (unsigned)h << 16);
}

// split 8 f32 -> hi/lo bf16x8 using v_cvt_pk_bf16_f32 (RNE)
__device__ __forceinline__ void split8(const float4& A, const float4& B,
                                       bf16x8& h8, bf16x8& l8) {
    const float f[8] = {A.x, A.y, A.z, A.w, B.x, B.y, B.z, B.w};
    unsigned hu[4], lu[4];
#pragma unroll
    for (int p = 0; p < 4; ++p) {
        unsigned uh;
        asm("v_cvt_pk_bf16_f32 %0, %1, %2" : "=v"(uh) : "v"(f[2*p]), "v"(f[2*p+1]));
        const float h0 = __builtin_bit_cast(float, uh << 16);
        const float h1 = __builtin_bit_cast(float, uh & 0xffff0000u);
        const float l0 = f[2*p] - h0;
        const float l1 = f[2*p+1] - h1;
        unsigned ul;
        asm("v_cvt_pk_bf16_f32 %0, %1, %2" : "=v"(ul) : "v"(l0), "v"(l1));
        hu[p] = uh; lu[p] = ul;
    }
    uint4 vh = make_uint4(hu[0], hu[1], hu[2], hu[3]);
    uint4 vl = make_uint4(lu[0], lu[1], lu[2], lu[3]);
    h8 = __builtin_bit_cast(bf16x8, vh);
    l8 = __builtin_bit_cast(bf16x8, vl);
}

// ---------------------------------------------------------------------------
// Prep: W [2048][245] fp32 -> wtp packed fragment-major bf16 hi/lo.
// ---------------------------------------------------------------------------
__global__ __launch_bounds__(256)
void prep_pack(const float* __restrict__ W,
               unsigned* __restrict__ cnt,
               unsigned short* __restrict__ wtp)
{
    if (blockIdx.x == 0 && blockIdx.y == 0 && threadIdx.x == 0) *cnt = 0u;

    const int c   = blockIdx.x;          // 0..31
    const int fcg = blockIdx.y;          // 0..15
    const int tid = threadIdx.x;
    const int ks   = tid >> 7;           // 0..1
    const int hl   = (tid >> 6) & 1;     // 0..1
    const int lane = tid & 63;

    const int row = fcg * 16 + (lane & 15);
    const int kb  = c * 64 + ks * 32 + (lane >> 4) * 8;

    unsigned short v[8];
#pragma unroll
    for (int j = 0; j < 8; ++j) {
        const float f = (row < T_N) ? W[(long)(kb + j) * T_N + row] : 0.0f;
        const unsigned short h = bf16_rne(f);
        v[j] = hl ? bf16_rne(f - bf16_to_f(h)) : h;
    }
    const long off = (long)c * P_C + (long)fcg * P_FCG + ks * P_KS
                     + hl * P_HL + lane * 8;
    *reinterpret_cast<uint4*>(wtp + off) = *reinterpret_cast<const uint4*>(v);
}

// ---------------------------------------------------------------------------
// Dedicated x -> out_x streaming copy (pure pattern, HBM-BW-bound).
// ---------------------------------------------------------------------------
__global__ __launch_bounds__(256)
void copy_x(const float4* __restrict__ in, float4* __restrict__ out, int n)
{
    long i = (long)blockIdx.x * blockDim.x + threadIdx.x;
    const long stride = (long)gridDim.x * blockDim.x;
    for (; i < n; i += stride) out[i] = in[i];
}

// ---------------------------------------------------------------------------
// Router GEMM — barrier-free dataflow (round-15 structure), NO passthrough:
//   reads x + packed wtp; writes only probs/coords/flags. A fragments
//   straight from global; packed fragment-major B per k-step (1 KB
//   wave-contiguous); split-bf16 3-pass MFMA; LDS only for epilogue.
// ---------------------------------------------------------------------------
__global__ __launch_bounds__(512, 2)
void router_gemm(const float* __restrict__ x,
                 const unsigned short* __restrict__ wtp,
                 const float* __restrict__ br,
                 const int*   __restrict__ conn,
                 float* __restrict__ out_p,
                 float* __restrict__ out_n,
                 unsigned* __restrict__ cnt,
                 unsigned* __restrict__ list)
{
    __shared__ float slog[32 * 260];     // 33.3 KB (epilogue only)

    const int tid  = threadIdx.x;
    const int lane = tid & 63;
    const int wid  = tid >> 6;           // 0..7
    const int wr   = wid >> 2;           // 0..1 (row half)
    const int wc   = wid & 3;            // 0..3 (col quarter)
    const int m16  = lane & 15;
    const int kq   = lane >> 4;          // 0..3
    const long row0 = (long)blockIdx.x * BM;

    f32x4 acc[2][4];
#pragma unroll
    for (int fr = 0; fr < 2; ++fr)
#pragma unroll
        for (int fc = 0; fc < 4; ++fc)
            acc[fr][fc] = (f32x4){0.f, 0.f, 0.f, 0.f};

    const float* a0 = x + (row0 + wr * 32 + m16) * (long)D_DIM + kq * 8;
    const float* a1 = a0 + 16 * D_DIM;

    for (int c = 0; c < NCH; ++c) {
        const int k0 = c * 64;
        const unsigned short* pc = wtp + (long)c * P_C
                                   + (long)(wc * 4) * P_FCG + lane * 8;
#pragma unroll
        for (int ks = 0; ks < 2; ++ks) {
            const int ko = k0 + ks * 32;
            // ---- A fragments straight from global ----
            float4 r00 = *reinterpret_cast<const float4*>(a0 + ko);
            float4 r01 = *reinterpret_cast<const float4*>(a0 + ko + 4);
            float4 r10 = *reinterpret_cast<const float4*>(a1 + ko);
            float4 r11 = *reinterpret_cast<const float4*>(a1 + ko + 4);
            // ---- packed B fragments (wave-contiguous 1 KB each) ----
            uint4 bh[4], bl[4];
            const unsigned short* pk = pc + ks * P_KS;
#pragma unroll
            for (int fc = 0; fc < 4; ++fc) {
                bh[fc] = *reinterpret_cast<const uint4*>(pk + fc * P_FCG);
                bl[fc] = *reinterpret_cast<const uint4*>(pk + fc * P_FCG + P_HL);
            }
            // ---- convert + MFMA (hi*hi, lo*hi, hi*lo) ----
            bf16x8 ah0, al0, ah1, al1;
            split8(r00, r01, ah0, al0);
            split8(r10, r11, ah1, al1);
#pragma unroll
            for (int fc = 0; fc < 4; ++fc) {
                const bf16x8 bhv = __builtin_bit_cast(bf16x8, bh[fc]);
                const bf16x8 blv = __builtin_bit_cast(bf16x8, bl[fc]);
                acc[0][fc] = __builtin_amdgcn_mfma_f32_16x16x32_bf16(ah0, bhv, acc[0][fc], 0, 0, 0);
                acc[1][fc] = __builtin_amdgcn_mfma_f32_16x16x32_bf16(ah1, bhv, acc[1][fc], 0, 0, 0);
                acc[0][fc] = __builtin_amdgcn_mfma_f32_16x16x32_bf16(al0, bhv, acc[0][fc], 0, 0, 0);
                acc[1][fc] = __builtin_amdgcn_mfma_f32_16x16x32_bf16(al1, bhv, acc[1][fc], 0, 0, 0);
                acc[0][fc] = __builtin_amdgcn_mfma_f32_16x16x32_bf16(ah0, blv, acc[0][fc], 0, 0, 0);
                acc[1][fc] = __builtin_amdgcn_mfma_f32_16x16x32_bf16(ah1, blv, acc[1][fc], 0, 0, 0);
            }
        }
    }

    // ---- epilogue: two 32-row halves; register-resident softmax/top-8 ----
#pragma unroll 1
    for (int h = 0; h < 2; ++h) {
        __syncthreads();
        if (wr == h) {
#pragma unroll
            for (int fr = 0; fr < 2; ++fr)
#pragma unroll
                for (int fc = 0; fc < 4; ++fc)
#pragma unroll
                    for (int r = 0; r < 4; ++r) {
                        const int rloc = fr * 16 + kq * 4 + r;     // 0..31
                        const int col  = wc * 64 + fc * 16 + m16;
                        float v = acc[fr][fc][r];
                        v = (col < T_N) ? v + br[col] : -1e30f;
                        slog[rloc * 260 + col] = v;
                    }
        }
        __syncthreads();

        const int rloc = tid >> 4;          // 0..31
        const int sub  = tid & 15;          // 16 threads per row
        const long gr  = row0 + h * 32 + rloc;
        const float* base = &slog[rloc * 260];

        float vals[16];
#pragma unroll
        for (int t = 0; t < 16; ++t) vals[t] = base[sub + 16 * t];

        float m = -INFINITY;
#pragma unroll
        for (int t = 0; t < 16; ++t) m = fmaxf(m, vals[t]);
#pragma unroll
        for (int d = 8; d >= 1; d >>= 1) m = fmaxf(m, __shfl_xor(m, d, 16));

        float e[16]; float s = 0.f;
#pragma unroll
        for (int t = 0; t < 16; ++t) { e[t] = expf(vals[t] - m); s += e[t]; }
#pragma unroll
        for (int d = 8; d >= 1; d >>= 1) s += __shfl_xor(s, d, 16);
        const float inv = 1.0f / s;

        unsigned chosen = 0u;
        float prev = INFINITY;
        int flag = 0;
#pragma unroll 1
        for (int k = 0; k < TOPK + 1; ++k) {
            float bv = -1.f; int bt = 0;
#pragma unroll
            for (int t = 0; t < 16; ++t)
                if (!((chosen >> t) & 1u) && e[t] > bv) { bv = e[t]; bt = t; }
            int bcol = sub + 16 * bt;
#pragma unroll
            for (int d = 8; d >= 1; d >>= 1) {
                const float ov = __shfl_xor(bv, d, 16);
                const int   oc = __shfl_xor(bcol, d, 16);
                if (ov > bv || (ov == bv && oc < bcol)) { bv = ov; bcol = oc; }
            }
            if (bv >= prev * 0.9998f) flag = 1;     // logit gap < 2e-4
            prev = bv;
            if (k < TOPK) {
                if ((bcol & 15) == sub) chosen |= 1u << (bcol >> 4);
                if (sub == 0) {
                    out_p[gr * TOPK + k] = bv * inv;
                    const int* cp = conn + bcol * 3;
                    out_n[(gr * TOPK + k) * 3 + 0] = (float)cp[0];
                    out_n[(gr * TOPK + k) * 3 + 1] = (float)cp[1];
                    out_n[(gr * TOPK + k) * 3 + 2] = (float)cp[2];
                }
            }
        }
        if (sub == 0 && flag) {
            unsigned idx = atomicAdd(cnt, 1u);
            if (idx < 32768u) list[idx] = (unsigned)gr;
        }
    }
}

// ---------------------------------------------------------------------------
// Refine: fp64 recompute for flagged tokens (round-7/8 proven: branchless
// clamped loads, MLP 16, 4 tokens/block, wave-parallel top-8).
// ---------------------------------------------------------------------------
#define RB 4
__global__ __launch_bounds__(512)
void refine_fp64(const float* __restrict__ x,
                 const float* __restrict__ W,
                 const float* __restrict__ br,
                 const int*   __restrict__ conn,
                 float* __restrict__ out_p,
                 float* __restrict__ out_n,
                 const unsigned* __restrict__ cnt,
                 const unsigned* __restrict__ list)
{
    __shared__ float  sx[RB][D_DIM];      // 32 KB
    __shared__ double spart[2][RB][256];  // 16 KB
    __shared__ double slog[RB][256];      // 8 KB

    const int tid  = threadIdx.x;
    const int col  = tid & 255;
    const int kh   = tid >> 8;            // 0..1
    const int colc = (col < T_N) ? col : (T_N - 1);   // branchless clamp
    const int lane = tid & 63;
    const int w    = tid >> 6;            // 0..7
    const unsigned count = min(*cnt, 32768u);

    for (unsigned g0 = (unsigned)blockIdx.x * RB; g0 < count;
         g0 += gridDim.x * RB) {
        const int nb = (int)min((unsigned)RB, count - g0);
        long toks[RB];
#pragma unroll
        for (int j = 0; j < RB; ++j) {
            const unsigned idx = (g0 + j < count) ? (g0 + j) : (count - 1);
            toks[j] = (long)list[idx];
            *reinterpret_cast<float4*>(&sx[j][tid * 4]) =
                *reinterpret_cast<const float4*>(x + toks[j] * D_DIM + tid * 4);
        }
        __syncthreads();

        const int kb = kh * 1024;
        double a0 = 0.0, a1 = 0.0, a2 = 0.0, a3 = 0.0;
        for (int k0 = 0; k0 < 1024; k0 += 16) {
            float wv[16];
#pragma unroll
            for (int i = 0; i < 16; ++i)
                wv[i] = W[(long)(kb + k0 + i) * T_N + colc];  // unconditional
#pragma unroll
            for (int i = 0; i < 16; i += 2) {
                const float2 x0 = *reinterpret_cast<const float2*>(&sx[0][kb + k0 + i]);
                const float2 x1 = *reinterpret_cast<const float2*>(&sx[1][kb + k0 + i]);
                const float2 x2 = *reinterpret_cast<const float2*>(&sx[2][kb + k0 + i]);
                const float2 x3 = *reinterpret_cast<const float2*>(&sx[3][kb + k0 + i]);
                const double w0 = (double)wv[i], w1 = (double)wv[i + 1];
                a0 += (double)x0.x * w0; a0 += (double)x0.y * w1;
                a1 += (double)x1.x * w0; a1 += (double)x1.y * w1;
                a2 += (double)x2.x * w0; a2 += (double)x2.y * w1;
                a3 += (double)x3.x * w0; a3 += (double)x3.y * w1;
            }
        }
        spart[kh][0][col] = a0;
        spart[kh][1][col] = a1;
        spart[kh][2][col] = a2;
        spart[kh][3][col] = a3;
        __syncthreads();

        if (tid < 256) {
#pragma unroll
            for (int j = 0; j < RB; ++j)
                slog[j][tid] = (tid < T_N)
                    ? spart[0][j][tid] + spart[1][j][tid] + (double)br[tid]
                    : -1.0e300;
        }
        __syncthreads();

        if (w < nb) {
            const long tok = toks[w];
            double v[4];
#pragma unroll
            for (int i = 0; i < 4; ++i) v[i] = slog[w][lane + 64 * i];
            double m = fmax(fmax(v[0], v[1]), fmax(v[2], v[3]));
#pragma unroll
            for (int off = 32; off >= 1; off >>= 1)
                m = fmax(m, __shfl_xor(m, off));
            double e[4]; double s = 0.0;
#pragma unroll
            for (int i = 0; i < 4; ++i) {
                e[i] = (v[i] > -1.0e299) ? exp(v[i] - m) : 0.0;
                s += e[i];
            }
#pragma unroll
            for (int off = 32; off >= 1; off >>= 1)
                s += __shfl_xor(s, off);
            const double invZ = 1.0 / s;

            int sel[TOPK];
#pragma unroll 1
            for (int k = 0; k < TOPK; ++k) {
                double bv = -1.0; int bi = 255;
#pragma unroll
                for (int i = 0; i < 4; ++i) {
                    const int t = lane + 64 * i;
                    bool used = false;
                    for (int q = 0; q < k; ++q) used |= (sel[q] == t);
                    if (!used && e[i] > bv) { bv = e[i]; bi = t; }
                }
#pragma unroll
                for (int off = 32; off >= 1; off >>= 1) {
                    const double ov = __shfl_xor(bv, off);
                    const int    oi = __shfl_xor(bi, off);
                    if (ov > bv || (ov == bv && oi < bi)) { bv = ov; bi = oi; }
                }
                sel[k] = bi;
                if (lane == 0) {
                    out_p[tok * TOPK + k] = (float)(bv * invZ);
                    const int* cp = conn + bi * 3;
                    out_n[(tok * TOPK + k) * 3 + 0] = (float)cp[0];
                    out_n[(tok * TOPK + k) * 3 + 1] = (float)cp[1];
                    out_n[(tok * TOPK + k) * 3 + 2] = (float)cp[2];
                }
            }
        }
        __syncthreads();
    }
}

extern "C" void kernel_launch(void* const* d_in, const int* in_sizes, int n_in,
                              void* d_out, int out_size, void* d_ws, size_t ws_size,
                              hipStream_t stream) {
    const float* x    = (const float*)d_in[0];
    const float* Wr   = (const float*)d_in[1];
    const float* br   = (const float*)d_in[2];
    const int*   conn = (const int*)d_in[3];

    float* out_x = (float*)d_out;
    float* out_p = out_x + (size_t)8 * 4096 * 2048;
    float* out_n = out_p + (size_t)8 * 4096 * 8;

    unsigned*       cnt  = (unsigned*)d_ws;
    unsigned*       list = (unsigned*)((char*)d_ws + WS_LIST_OFF);
    unsigned short* wtp  = (unsigned short*)((char*)d_ws + WS_WTP_OFF);

    hipLaunchKernelGGL(prep_pack, dim3(32, 16), dim3(256), 0, stream,
                       Wr, cnt, wtp);
    hipLaunchKernelGGL(router_gemm, dim3(32768 / BM), dim3(512), 0, stream,
                       x, wtp, br, conn, out_p, out_n, cnt, list);
    hipLaunchKernelGGL(copy_x, dim3(2048), dim3(256), 0, stream,
                       (const float4*)x, (float4*)out_x,
                       (int)((size_t)8 * 4096 * 2048 / 4));
    hipLaunchKernelGGL(refine_fp64, dim3(512), dim3(512), 0, stream,
                       x, Wr, br, conn, out_p, out_n, cnt, list);
}

// Round 19
// 426.905 us; speedup vs baseline: 3.7710x; 3.7710x over previous
//
#include <hip/hip_runtime.h>
#include <math.h>

#define D_DIM 2048
#define T_N   245
#define TOPK  8
#define BM    64
#define NCH   32              // 2048 / 64

typedef __attribute__((ext_vector_type(8))) __bf16 bf16x8;
typedef __attribute__((ext_vector_type(4))) float  f32x4;

// ws layout (~2.4 MB):
//   [0]        : unsigned counter
//   [256]      : token list, unsigned[32768] (128 KB)
//   [256K]     : wtp packed fragments, bf16 [32][16][2][2][64][8]  (2 MB)
#define WS_LIST_OFF   256
#define WS_WTP_OFF    (256 * 1024)

// packed strides (bf16 units)
#define P_C    32768          // 16*2*2*64*8
#define P_FCG  2048           // 2*2*64*8
#define P_KS   1024           // 2*64*8
#define P_HL   512            // 64*8

__device__ __forceinline__ unsigned short bf16_rne(float f) {
    unsigned u = __builtin_bit_cast(unsigned, f);
    u += 0x7FFFu + ((u >> 16) & 1u);
    return (unsigned short)(u >> 16);
}
__device__ __forceinline__ float bf16_to_f(unsigned short h) {
    return __builtin_bit_cast(float, (unsigned)h << 16);
}

// split 8 f32 -> hi/lo bf16x8 using v_cvt_pk_bf16_f32 (RNE)
__device__ __forceinline__ void split8(const float4& A, const float4& B,
                                       bf16x8& h8, bf16x8& l8) {
    const float f[8] = {A.x, A.y, A.z, A.w, B.x, B.y, B.z, B.w};
    unsigned hu[4], lu[4];
#pragma unroll
    for (int p = 0; p < 4; ++p) {
        unsigned uh;
        asm("v_cvt_pk_bf16_f32 %0, %1, %2" : "=v"(uh) : "v"(f[2*p]), "v"(f[2*p+1]));
        const float h0 = __builtin_bit_cast(float, uh << 16);
        const float h1 = __builtin_bit_cast(float, uh & 0xffff0000u);
        const float l0 = f[2*p] - h0;
        const float l1 = f[2*p+1] - h1;
        unsigned ul;
        asm("v_cvt_pk_bf16_f32 %0, %1, %2" : "=v"(ul) : "v"(l0), "v"(l1));
        hu[p] = uh; lu[p] = ul;
    }
    uint4 vh = make_uint4(hu[0], hu[1], hu[2], hu[3]);
    uint4 vl = make_uint4(lu[0], lu[1], lu[2], lu[3]);
    h8 = __builtin_bit_cast(bf16x8, vh);
    l8 = __builtin_bit_cast(bf16x8, vl);
}

// ---------------------------------------------------------------------------
// Prep: W [2048][245] fp32 -> wtp packed fragment-major bf16 hi/lo.
// ---------------------------------------------------------------------------
__global__ __launch_bounds__(256)
void prep_pack(const float* __restrict__ W,
               unsigned* __restrict__ cnt,
               unsigned short* __restrict__ wtp)
{
    if (blockIdx.x == 0 && blockIdx.y == 0 && threadIdx.x == 0) *cnt = 0u;

    const int c   = blockIdx.x;          // 0..31
    const int fcg = blockIdx.y;          // 0..15
    const int tid = threadIdx.x;
    const int ks   = tid >> 7;           // 0..1
    const int hl   = (tid >> 6) & 1;     // 0..1
    const int lane = tid & 63;

    const int row = fcg * 16 + (lane & 15);
    const int kb  = c * 64 + ks * 32 + (lane >> 4) * 8;

    unsigned short v[8];
#pragma unroll
    for (int j = 0; j < 8; ++j) {
        const float f = (row < T_N) ? W[(long)(kb + j) * T_N + row] : 0.0f;
        const unsigned short h = bf16_rne(f);
        v[j] = hl ? bf16_rne(f - bf16_to_f(h)) : h;
    }
    const long off = (long)c * P_C + (long)fcg * P_FCG + ks * P_KS
                     + hl * P_HL + lane * 8;
    *reinterpret_cast<uint4*>(wtp + off) = *reinterpret_cast<const uint4*>(v);
}

// ---------------------------------------------------------------------------
// Dedicated x -> out_x streaming copy (pure pattern, HBM-BW-bound).
// ---------------------------------------------------------------------------
__global__ __launch_bounds__(256)
void copy_x(const float4* __restrict__ in, float4* __restrict__ out, int n)
{
    long i = (long)blockIdx.x * blockDim.x + threadIdx.x;
    const long stride = (long)gridDim.x * blockDim.x;
    for (; i < n; i += stride) out[i] = in[i];
}

// ---------------------------------------------------------------------------
// Router GEMM — barrier-free dataflow, no passthrough (round-18 core, which
// measured ~100-150us). NEW epilogue: single-pass 64-row slog (66.5 KB),
// LOGIT-domain top-9 selection + SUBTRACTIVE gap flag (no exp-ratio edge
// cases), probs computed only for winners.
// ---------------------------------------------------------------------------
__global__ __launch_bounds__(512, 2)
void router_gemm(const float* __restrict__ x,
                 const unsigned short* __restrict__ wtp,
                 const float* __restrict__ br,
                 const int*   __restrict__ conn,
                 float* __restrict__ out_p,
                 float* __restrict__ out_n,
                 unsigned* __restrict__ cnt,
                 unsigned* __restrict__ list)
{
    __shared__ float slog[64 * 260];     // 66.5 KB (epilogue only)

    const int tid  = threadIdx.x;
    const int lane = tid & 63;
    const int wid  = tid >> 6;           // 0..7
    const int wr   = wid >> 2;           // 0..1 (row half)
    const int wc   = wid & 3;            // 0..3 (col quarter)
    const int m16  = lane & 15;
    const int kq   = lane >> 4;          // 0..3
    const long row0 = (long)blockIdx.x * BM;

    f32x4 acc[2][4];
#pragma unroll
    for (int fr = 0; fr < 2; ++fr)
#pragma unroll
        for (int fc = 0; fc < 4; ++fc)
            acc[fr][fc] = (f32x4){0.f, 0.f, 0.f, 0.f};

    const float* a0 = x + (row0 + wr * 32 + m16) * (long)D_DIM + kq * 8;
    const float* a1 = a0 + 16 * D_DIM;

    for (int c = 0; c < NCH; ++c) {
        const int k0 = c * 64;
        const unsigned short* pc = wtp + (long)c * P_C
                                   + (long)(wc * 4) * P_FCG + lane * 8;
#pragma unroll
        for (int ks = 0; ks < 2; ++ks) {
            const int ko = k0 + ks * 32;
            float4 r00 = *reinterpret_cast<const float4*>(a0 + ko);
            float4 r01 = *reinterpret_cast<const float4*>(a0 + ko + 4);
            float4 r10 = *reinterpret_cast<const float4*>(a1 + ko);
            float4 r11 = *reinterpret_cast<const float4*>(a1 + ko + 4);
            uint4 bh[4], bl[4];
            const unsigned short* pk = pc + ks * P_KS;
#pragma unroll
            for (int fc = 0; fc < 4; ++fc) {
                bh[fc] = *reinterpret_cast<const uint4*>(pk + fc * P_FCG);
                bl[fc] = *reinterpret_cast<const uint4*>(pk + fc * P_FCG + P_HL);
            }
            bf16x8 ah0, al0, ah1, al1;
            split8(r00, r01, ah0, al0);
            split8(r10, r11, ah1, al1);
#pragma unroll
            for (int fc = 0; fc < 4; ++fc) {
                const bf16x8 bhv = __builtin_bit_cast(bf16x8, bh[fc]);
                const bf16x8 blv = __builtin_bit_cast(bf16x8, bl[fc]);
                acc[0][fc] = __builtin_amdgcn_mfma_f32_16x16x32_bf16(ah0, bhv, acc[0][fc], 0, 0, 0);
                acc[1][fc] = __builtin_amdgcn_mfma_f32_16x16x32_bf16(ah1, bhv, acc[1][fc], 0, 0, 0);
                acc[0][fc] = __builtin_amdgcn_mfma_f32_16x16x32_bf16(al0, bhv, acc[0][fc], 0, 0, 0);
                acc[1][fc] = __builtin_amdgcn_mfma_f32_16x16x32_bf16(al1, bhv, acc[1][fc], 0, 0, 0);
                acc[0][fc] = __builtin_amdgcn_mfma_f32_16x16x32_bf16(ah0, blv, acc[0][fc], 0, 0, 0);
                acc[1][fc] = __builtin_amdgcn_mfma_f32_16x16x32_bf16(ah1, blv, acc[1][fc], 0, 0, 0);
            }
        }
    }

    // ---- epilogue: every thread writes its logits (no conditional) ----
#pragma unroll
    for (int fr = 0; fr < 2; ++fr)
#pragma unroll
        for (int fc = 0; fc < 4; ++fc)
#pragma unroll
            for (int r = 0; r < 4; ++r) {
                const int rloc = wr * 32 + fr * 16 + kq * 4 + r;   // 0..63
                const int col  = wc * 64 + fc * 16 + m16;
                float v = acc[fr][fc][r];
                v = (col < T_N) ? v + br[col] : -1e30f;
                slog[rloc * 260 + col] = v;
            }
    __syncthreads();

    // ---- per-row softmax + top-8 + gap flag: 8 threads/row, 32 cols each,
    //      selection in LOGIT domain (exp monotone), subtractive gap test ----
    {
        const int rloc = tid >> 3;          // 0..63
        const int sub  = tid & 7;           // 0..7
        const long gr  = row0 + rloc;
        const float* base = &slog[rloc * 260];

        float vals[32];
#pragma unroll
        for (int t = 0; t < 32; ++t) vals[t] = base[sub + 8 * t];

        float m = -INFINITY;
#pragma unroll
        for (int t = 0; t < 32; ++t) m = fmaxf(m, vals[t]);
#pragma unroll
        for (int d = 4; d >= 1; d >>= 1) m = fmaxf(m, __shfl_xor(m, d, 8));

        float s = 0.f;
#pragma unroll
        for (int t = 0; t < 32; ++t) s += expf(vals[t] - m);
#pragma unroll
        for (int d = 4; d >= 1; d >>= 1) s += __shfl_xor(s, d, 8);
        const float inv = 1.0f / s;

        unsigned chosen = 0u;
        float prev = INFINITY;
        int flag = 0;
#pragma unroll 1
        for (int k = 0; k < TOPK + 1; ++k) {
            float bv = -INFINITY; int bt = 0;
#pragma unroll
            for (int t = 0; t < 32; ++t)
                if (!((chosen >> t) & 1u) && vals[t] > bv) { bv = vals[t]; bt = t; }
            int bcol = sub + 8 * bt;
#pragma unroll
            for (int d = 4; d >= 1; d >>= 1) {
                const float ov = __shfl_xor(bv, d, 8);
                const int   oc = __shfl_xor(bcol, d, 8);
                if (ov > bv || (ov == bv && oc < bcol)) { bv = ov; bcol = oc; }
            }
            if (prev - bv <= 2e-4f) flag = 1;   // logit gap (INF-bv at k=0 safe)
            prev = bv;
            if (k < TOPK) {
                if ((bcol & 7) == sub) chosen |= 1u << (bcol >> 3);
                if (sub == 0) {
                    out_p[gr * TOPK + k] = expf(bv - m) * inv;
                    const int* cp = conn + bcol * 3;
                    out_n[(gr * TOPK + k) * 3 + 0] = (float)cp[0];
                    out_n[(gr * TOPK + k) * 3 + 1] = (float)cp[1];
                    out_n[(gr * TOPK + k) * 3 + 2] = (float)cp[2];
                }
            }
        }
        if (sub == 0 && flag) {
            unsigned idx = atomicAdd(cnt, 1u);
            if (idx < 32768u) list[idx] = (unsigned)gr;
        }
    }
}

// ---------------------------------------------------------------------------
// Refine: fp64 recompute for flagged tokens (round-7/8 proven: branchless
// clamped loads, MLP 16, 4 tokens/block, wave-parallel top-8).
// ---------------------------------------------------------------------------
#define RB 4
__global__ __launch_bounds__(512)
void refine_fp64(const float* __restrict__ x,
                 const float* __restrict__ W,
                 const float* __restrict__ br,
                 const int*   __restrict__ conn,
                 float* __restrict__ out_p,
                 float* __restrict__ out_n,
                 const unsigned* __restrict__ cnt,
                 const unsigned* __restrict__ list)
{
    __shared__ float  sx[RB][D_DIM];      // 32 KB
    __shared__ double spart[2][RB][256];  // 16 KB
    __shared__ double slog[RB][256];      // 8 KB

    const int tid  = threadIdx.x;
    const int col  = tid & 255;
    const int kh   = tid >> 8;            // 0..1
    const int colc = (col < T_N) ? col : (T_N - 1);   // branchless clamp
    const int lane = tid & 63;
    const int w    = tid >> 6;            // 0..7
    const unsigned count = min(*cnt, 32768u);

    for (unsigned g0 = (unsigned)blockIdx.x * RB; g0 < count;
         g0 += gridDim.x * RB) {
        const int nb = (int)min((unsigned)RB, count - g0);
        long toks[RB];
#pragma unroll
        for (int j = 0; j < RB; ++j) {
            const unsigned idx = (g0 + j < count) ? (g0 + j) : (count - 1);
            toks[j] = (long)list[idx];
            *reinterpret_cast<float4*>(&sx[j][tid * 4]) =
                *reinterpret_cast<const float4*>(x + toks[j] * D_DIM + tid * 4);
        }
        __syncthreads();

        const int kb = kh * 1024;
        double a0 = 0.0, a1 = 0.0, a2 = 0.0, a3 = 0.0;
        for (int k0 = 0; k0 < 1024; k0 += 16) {
            float wv[16];
#pragma unroll
            for (int i = 0; i < 16; ++i)
                wv[i] = W[(long)(kb + k0 + i) * T_N + colc];  // unconditional
#pragma unroll
            for (int i = 0; i < 16; i += 2) {
                const float2 x0 = *reinterpret_cast<const float2*>(&sx[0][kb + k0 + i]);
                const float2 x1 = *reinterpret_cast<const float2*>(&sx[1][kb + k0 + i]);
                const float2 x2 = *reinterpret_cast<const float2*>(&sx[2][kb + k0 + i]);
                const float2 x3 = *reinterpret_cast<const float2*>(&sx[3][kb + k0 + i]);
                const double w0 = (double)wv[i], w1 = (double)wv[i + 1];
                a0 += (double)x0.x * w0; a0 += (double)x0.y * w1;
                a1 += (double)x1.x * w0; a1 += (double)x1.y * w1;
                a2 += (double)x2.x * w0; a2 += (double)x2.y * w1;
                a3 += (double)x3.x * w0; a3 += (double)x3.y * w1;
            }
        }
        spart[kh][0][col] = a0;
        spart[kh][1][col] = a1;
        spart[kh][2][col] = a2;
        spart[kh][3][col] = a3;
        __syncthreads();

        if (tid < 256) {
#pragma unroll
            for (int j = 0; j < RB; ++j)
                slog[j][tid] = (tid < T_N)
                    ? spart[0][j][tid] + spart[1][j][tid] + (double)br[tid]
                    : -1.0e300;
        }
        __syncthreads();

        if (w < nb) {
            const long tok = toks[w];
            double v[4];
#pragma unroll
            for (int i = 0; i < 4; ++i) v[i] = slog[w][lane + 64 * i];
            double m = fmax(fmax(v[0], v[1]), fmax(v[2], v[3]));
#pragma unroll
            for (int off = 32; off >= 1; off >>= 1)
                m = fmax(m, __shfl_xor(m, off));
            double e[4]; double s = 0.0;
#pragma unroll
            for (int i = 0; i < 4; ++i) {
                e[i] = (v[i] > -1.0e299) ? exp(v[i] - m) : 0.0;
                s += e[i];
            }
#pragma unroll
            for (int off = 32; off >= 1; off >>= 1)
                s += __shfl_xor(s, off);
            const double invZ = 1.0 / s;

            int sel[TOPK];
#pragma unroll 1
            for (int k = 0; k < TOPK; ++k) {
                double bv = -1.0; int bi = 255;
#pragma unroll
                for (int i = 0; i < 4; ++i) {
                    const int t = lane + 64 * i;
                    bool used = false;
                    for (int q = 0; q < k; ++q) used |= (sel[q] == t);
                    if (!used && e[i] > bv) { bv = e[i]; bi = t; }
                }
#pragma unroll
                for (int off = 32; off >= 1; off >>= 1) {
                    const double ov = __shfl_xor(bv, off);
                    const int    oi = __shfl_xor(bi, off);
                    if (ov > bv || (ov == bv && oi < bi)) { bv = ov; bi = oi; }
                }
                sel[k] = bi;
                if (lane == 0) {
                    out_p[tok * TOPK + k] = (float)(bv * invZ);
                    const int* cp = conn + bi * 3;
                    out_n[(tok * TOPK + k) * 3 + 0] = (float)cp[0];
                    out_n[(tok * TOPK + k) * 3 + 1] = (float)cp[1];
                    out_n[(tok * TOPK + k) * 3 + 2] = (float)cp[2];
                }
            }
        }
        __syncthreads();
    }
}

extern "C" void kernel_launch(void* const* d_in, const int* in_sizes, int n_in,
                              void* d_out, int out_size, void* d_ws, size_t ws_size,
                              hipStream_t stream) {
    const float* x    = (const float*)d_in[0];
    const float* Wr   = (const float*)d_in[1];
    const float* br   = (const float*)d_in[2];
    const int*   conn = (const int*)d_in[3];

    float* out_x = (float*)d_out;
    float* out_p = out_x + (size_t)8 * 4096 * 2048;
    float* out_n = out_p + (size_t)8 * 4096 * 8;

    unsigned*       cnt  = (unsigned*)d_ws;
    unsigned*       list = (unsigned*)((char*)d_ws + WS_LIST_OFF);
    unsigned short* wtp  = (unsigned short*)((char*)d_ws + WS_WTP_OFF);

    hipLaunchKernelGGL(prep_pack, dim3(32, 16), dim3(256), 0, stream,
                       Wr, cnt, wtp);
    hipLaunchKernelGGL(router_gemm, dim3(32768 / BM), dim3(512), 0, stream,
                       x, wtp, br, conn, out_p, out_n, cnt, list);
    hipLaunchKernelGGL(copy_x, dim3(2048), dim3(256), 0, stream,
                       (const float4*)x, (float4*)out_x,
                       (int)((size_t)8 * 4096 * 2048 / 4));
    hipLaunchKernelGGL(refine_fp64, dim3(1024), dim3(512), 0, stream,
                       x, Wr, br, conn, out_p, out_n, cnt, list);
}

// Round 20
// 300.192 us; speedup vs baseline: 5.3628x; 1.4221x over previous
//
#include <hip/hip_runtime.h>
#include <math.h>

#define D_DIM 2048
#define T_N   245
#define TOPK  8
#define BM    64
#define NC2   64              // 2048 / 32 (BK=32 chunks)

typedef __attribute__((ext_vector_type(8))) __bf16 bf16x8;
typedef __attribute__((ext_vector_type(4))) float  f32x4;

// ws layout (~2.4 MB):
//   [0]        : unsigned counter
//   [256]      : token list, unsigned[32768] (128 KB)
//   [256K]     : wtp packed fragments, bf16 [64 c2][16 fcg][2 hl][64][8] (2 MB)
#define WS_LIST_OFF   256
#define WS_WTP_OFF    (256 * 1024)

// packed strides (bf16 units) — BK=32-chunk-major, chunk = 32 KB contiguous
#define Q_C    16384          // 16*2*64*8
#define Q_FCG  1024           // 2*64*8
#define Q_HL   512            // 64*8

__device__ __forceinline__ unsigned short bf16_rne(float f) {
    unsigned u = __builtin_bit_cast(unsigned, f);
    u += 0x7FFFu + ((u >> 16) & 1u);
    return (unsigned short)(u >> 16);
}
__device__ __forceinline__ float bf16_to_f(unsigned short h) {
    return __builtin_bit_cast(float, (unsigned)h << 16);
}

// async global->LDS, 16 B per lane (1 KB per wave-instr)
__device__ __forceinline__ void gll16(const void* g, void* l) {
    __builtin_amdgcn_global_load_lds(
        (const __attribute__((address_space(1))) void*)g,
        (__attribute__((address_space(3))) void*)l, 16, 0, 0);
}

// split 8 f32 -> hi/lo bf16x8 using v_cvt_pk_bf16_f32 (RNE)
__device__ __forceinline__ void split8(const float4& A, const float4& B,
                                       bf16x8& h8, bf16x8& l8) {
    const float f[8] = {A.x, A.y, A.z, A.w, B.x, B.y, B.z, B.w};
    unsigned hu[4], lu[4];
#pragma unroll
    for (int p = 0; p < 4; ++p) {
        unsigned uh;
        asm("v_cvt_pk_bf16_f32 %0, %1, %2" : "=v"(uh) : "v"(f[2*p]), "v"(f[2*p+1]));
        const float h0 = __builtin_bit_cast(float, uh << 16);
        const float h1 = __builtin_bit_cast(float, uh & 0xffff0000u);
        const float l0 = f[2*p] - h0;
        const float l1 = f[2*p+1] - h1;
        unsigned ul;
        asm("v_cvt_pk_bf16_f32 %0, %1, %2" : "=v"(ul) : "v"(l0), "v"(l1));
        hu[p] = uh; lu[p] = ul;
    }
    uint4 vh = make_uint4(hu[0], hu[1], hu[2], hu[3]);
    uint4 vl = make_uint4(lu[0], lu[1], lu[2], lu[3]);
    h8 = __builtin_bit_cast(bf16x8, vh);
    l8 = __builtin_bit_cast(bf16x8, vl);
}

// ---------------------------------------------------------------------------
// Prep: W [2048][245] fp32 -> wtp, BK=32-chunk-major packed bf16 hi/lo.
// Element (c2, fcg, hl, lane, j) = split(W[k][row]),
//   row = fcg*16 + (lane&15), k = c2*32 + (lane>>4)*8 + j.
// ---------------------------------------------------------------------------
__global__ __launch_bounds__(256)
void prep_pack(const float* __restrict__ W,
               unsigned* __restrict__ cnt,
               unsigned short* __restrict__ wtp)
{
    if (blockIdx.x == 0 && blockIdx.y == 0 && threadIdx.x == 0) *cnt = 0u;

    const int c   = blockIdx.x;          // 0..31
    const int fcg = blockIdx.y;          // 0..15
    const int tid = threadIdx.x;
    const int ks   = tid >> 7;           // 0..1
    const int hl   = (tid >> 6) & 1;     // 0..1
    const int lane = tid & 63;

    const int c2  = c * 2 + ks;          // 0..63
    const int row = fcg * 16 + (lane & 15);
    const int kb  = c2 * 32 + (lane >> 4) * 8;

    unsigned short v[8];
#pragma unroll
    for (int j = 0; j < 8; ++j) {
        const float f = (row < T_N) ? W[(long)(kb + j) * T_N + row] : 0.0f;
        const unsigned short h = bf16_rne(f);
        v[j] = hl ? bf16_rne(f - bf16_to_f(h)) : h;
    }
    const long off = (long)c2 * Q_C + (long)fcg * Q_FCG + hl * Q_HL + lane * 8;
    *reinterpret_cast<uint4*>(wtp + off) = *reinterpret_cast<const uint4*>(v);
}

// ---------------------------------------------------------------------------
// Main router — LDS-shared B (the 3x VMEM-instruction cut):
//   Per chunk per WAVE: 4 gll (B, 1KB each) + 1 gll (A) + 1 store = 6 VMEM
//   wave-instr (vs 20 in rounds 8-14; TA issue rate was the uniform wall).
//   B staged ONCE per block into LDS (32 KB/chunk, double-buffered), all
//   waves ds_read their fragments. A staged via swizzled-source gll
//   (round-14 proven, &7 variant). x passthrough from LDS-A, full-line.
//   One __syncthreads per chunk; glls issued at chunk top, drained at end.
//   LDS 80 KB -> exactly 2 blocks/CU. Epilogue (66.5 KB) reuses the space.
// ---------------------------------------------------------------------------
__global__ __launch_bounds__(512, 4)
void router_mfma(const float* __restrict__ x,
                 const unsigned short* __restrict__ wtp,
                 const float* __restrict__ br,
                 const int*   __restrict__ conn,
                 float* __restrict__ out_x,
                 float* __restrict__ out_p,
                 float* __restrict__ out_n,
                 unsigned* __restrict__ cnt,
                 unsigned* __restrict__ list)
{
    __shared__ char smem[81920];         // A dbuf 16 KB | B dbuf 64 KB
    float*          Abuf = (float*)smem;                    // [2][64][32] f32
    unsigned short* Bbuf = (unsigned short*)(smem + 16384); // [2][16384] bf16
    float*          slog = (float*)smem;                    // epilogue [64][260]

    const int tid  = threadIdx.x;
    const int lane = tid & 63;
    const int wid  = tid >> 6;           // 0..7
    const int wr   = wid >> 2;           // 0..1 (row half)
    const int wc   = wid & 3;            // 0..3 (col quarter)
    const int m16  = lane & 15;
    const int kq   = lane >> 4;          // 0..3
    const long row0 = (long)blockIdx.x * BM;

    f32x4 acc[2][4];
#pragma unroll
    for (int fr = 0; fr < 2; ++fr)
#pragma unroll
        for (int fc = 0; fc < 4; ++fc)
            acc[fr][fc] = (f32x4){0.f, 0.f, 0.f, 0.f};

    // stage A chunk c2 into Abuf[b]: 1 gll/wave (8 rows x 128 B, swizzled src)
    auto stageA = [&](int c2, int b) {
        const int r  = wid * 8 + (lane >> 3);
        const int su = (lane & 7) ^ (r & 7);
        gll16(x + (row0 + r) * (long)D_DIM + c2 * 32 + su * 4,
              Abuf + b * 2048 + wid * 8 * 32);
    };
    // stage B chunk c2 into Bbuf[b]: 4 gll/wave (linear 32 KB copy)
    auto stageB = [&](int c2, int b) {
        const unsigned short* src = wtp + (long)c2 * Q_C + wid * 2048;
        unsigned short*       dst = Bbuf + b * 16384 + wid * 2048;
#pragma unroll
        for (int q = 0; q < 4; ++q)
            gll16(src + q * 512 + lane * 8, dst + q * 512);
    };

    // ---- prologue ----
    stageA(0, 0);
    stageB(0, 0);
    __syncthreads();

    for (int c2 = 0; c2 < NC2; ++c2) {
        const int b = c2 & 1;

        // ---- 1. issue next chunk's staging (drained at end barrier) ----
        if (c2 + 1 < NC2) {
            stageA(c2 + 1, b ^ 1);
            stageB(c2 + 1, b ^ 1);
        }

        // ---- 2. x passthrough: full-line stores from LDS-A ----
        {
            const int row = tid >> 3;        // 0..63
            const int lu  = tid & 7;
            float4 v = *reinterpret_cast<const float4*>(
                Abuf + b * 2048 + row * 32 + ((lu ^ (row & 7)) * 4));
            *reinterpret_cast<float4*>(
                out_x + (row0 + row) * (long)D_DIM + c2 * 32 + lu * 4) = v;
        }

        // ---- 3. consume: A/B from LDS, split-bf16 3-pass MFMA ----
        bf16x8 ah[2], al[2];
#pragma unroll
        for (int fr = 0; fr < 2; ++fr) {
            const int row = wr * 32 + fr * 16 + m16;
            const float* Ar = Abuf + b * 2048 + row * 32;
            float4 r0 = *reinterpret_cast<const float4*>(
                Ar + (((kq * 2)     ^ (row & 7)) * 4));
            float4 r1 = *reinterpret_cast<const float4*>(
                Ar + (((kq * 2 + 1) ^ (row & 7)) * 4));
            split8(r0, r1, ah[fr], al[fr]);
        }
#pragma unroll
        for (int fc = 0; fc < 4; ++fc) {
            const unsigned short* Bp = Bbuf + b * 16384
                                       + (wc * 4 + fc) * Q_FCG + lane * 8;
            const bf16x8 bhv = *reinterpret_cast<const bf16x8*>(Bp);
            const bf16x8 blv = *reinterpret_cast<const bf16x8*>(Bp + Q_HL);
#pragma unroll
            for (int fr = 0; fr < 2; ++fr) {
                acc[fr][fc] = __builtin_amdgcn_mfma_f32_16x16x32_bf16(ah[fr], bhv, acc[fr][fc], 0, 0, 0);
                acc[fr][fc] = __builtin_amdgcn_mfma_f32_16x16x32_bf16(al[fr], bhv, acc[fr][fc], 0, 0, 0);
                acc[fr][fc] = __builtin_amdgcn_mfma_f32_16x16x32_bf16(ah[fr], blv, acc[fr][fc], 0, 0, 0);
            }
        }

        // ---- 4. barrier: drains glls(c2+1)+stores, seals buffer swap ----
        __syncthreads();
    }

    // ---- epilogue: logits -> slog (overwrites A/B LDS; barrier above) ----
#pragma unroll
    for (int fr = 0; fr < 2; ++fr)
#pragma unroll
        for (int fc = 0; fc < 4; ++fc)
#pragma unroll
            for (int r = 0; r < 4; ++r) {
                const int rloc = wr * 32 + fr * 16 + kq * 4 + r;   // 0..63
                const int col  = wc * 64 + fc * 16 + m16;
                float v = acc[fr][fc][r];
                v = (col < T_N) ? v + br[col] : -1e30f;
                slog[rloc * 260 + col] = v;
            }
    __syncthreads();

    // ---- per-row softmax + top-8 + gap flag (8 thr/row, logit domain) ----
    {
        const int rloc = tid >> 3;          // 0..63
        const int sub  = tid & 7;           // 0..7
        const long gr  = row0 + rloc;
        const float* base = &slog[rloc * 260];

        float vals[32];
#pragma unroll
        for (int t = 0; t < 32; ++t) vals[t] = base[sub + 8 * t];

        float m = -INFINITY;
#pragma unroll
        for (int t = 0; t < 32; ++t) m = fmaxf(m, vals[t]);
#pragma unroll
        for (int d = 4; d >= 1; d >>= 1) m = fmaxf(m, __shfl_xor(m, d, 8));

        float s = 0.f;
#pragma unroll
        for (int t = 0; t < 32; ++t) s += expf(vals[t] - m);
#pragma unroll
        for (int d = 4; d >= 1; d >>= 1) s += __shfl_xor(s, d, 8);
        const float inv = 1.0f / s;

        unsigned chosen = 0u;
        float prev = INFINITY;
        int flag = 0;
#pragma unroll 1
        for (int k = 0; k < TOPK + 1; ++k) {
            float bv = -INFINITY; int bt = 0;
#pragma unroll
            for (int t = 0; t < 32; ++t)
                if (!((chosen >> t) & 1u) && vals[t] > bv) { bv = vals[t]; bt = t; }
            int bcol = sub + 8 * bt;
#pragma unroll
            for (int d = 4; d >= 1; d >>= 1) {
                const float ov = __shfl_xor(bv, d, 8);
                const int   oc = __shfl_xor(bcol, d, 8);
                if (ov > bv || (ov == bv && oc < bcol)) { bv = ov; bcol = oc; }
            }
            if (prev - bv <= 2e-4f) flag = 1;   // logit gap (INF at k=0 safe)
            prev = bv;
            if (k < TOPK) {
                if ((bcol & 7) == sub) chosen |= 1u << (bcol >> 3);
                if (sub == 0) {
                    out_p[gr * TOPK + k] = expf(bv - m) * inv;
                    const int* cp = conn + bcol * 3;
                    out_n[(gr * TOPK + k) * 3 + 0] = (float)cp[0];
                    out_n[(gr * TOPK + k) * 3 + 1] = (float)cp[1];
                    out_n[(gr * TOPK + k) * 3 + 2] = (float)cp[2];
                }
            }
        }
        if (sub == 0 && flag) {
            unsigned idx = atomicAdd(cnt, 1u);
            if (idx < 32768u) list[idx] = (unsigned)gr;
        }
    }
}

// ---------------------------------------------------------------------------
// Refine: fp64 recompute for flagged tokens (round-7/8 proven: branchless
// clamped loads, MLP 16, 4 tokens/block, wave-parallel top-8).
// ---------------------------------------------------------------------------
#define RB 4
__global__ __launch_bounds__(512)
void refine_fp64(const float* __restrict__ x,
                 const float* __restrict__ W,
                 const float* __restrict__ br,
                 const int*   __restrict__ conn,
                 float* __restrict__ out_p,
                 float* __restrict__ out_n,
                 const unsigned* __restrict__ cnt,
                 const unsigned* __restrict__ list)
{
    __shared__ float  sx[RB][D_DIM];      // 32 KB
    __shared__ double spart[2][RB][256];  // 16 KB
    __shared__ double slog[RB][256];      // 8 KB

    const int tid  = threadIdx.x;
    const int col  = tid & 255;
    const int kh   = tid >> 8;            // 0..1
    const int colc = (col < T_N) ? col : (T_N - 1);   // branchless clamp
    const int lane = tid & 63;
    const int w    = tid >> 6;            // 0..7
    const unsigned count = min(*cnt, 32768u);

    for (unsigned g0 = (unsigned)blockIdx.x * RB; g0 < count;
         g0 += gridDim.x * RB) {
        const int nb = (int)min((unsigned)RB, count - g0);
        long toks[RB];
#pragma unroll
        for (int j = 0; j < RB; ++j) {
            const unsigned idx = (g0 + j < count) ? (g0 + j) : (count - 1);
            toks[j] = (long)list[idx];
            *reinterpret_cast<float4*>(&sx[j][tid * 4]) =
                *reinterpret_cast<const float4*>(x + toks[j] * D_DIM + tid * 4);
        }
        __syncthreads();

        const int kb = kh * 1024;
        double a0 = 0.0, a1 = 0.0, a2 = 0.0, a3 = 0.0;
        for (int k0 = 0; k0 < 1024; k0 += 16) {
            float wv[16];
#pragma unroll
            for (int i = 0; i < 16; ++i)
                wv[i] = W[(long)(kb + k0 + i) * T_N + colc];  // unconditional
#pragma unroll
            for (int i = 0; i < 16; i += 2) {
                const float2 x0 = *reinterpret_cast<const float2*>(&sx[0][kb + k0 + i]);
                const float2 x1 = *reinterpret_cast<const float2*>(&sx[1][kb + k0 + i]);
                const float2 x2 = *reinterpret_cast<const float2*>(&sx[2][kb + k0 + i]);
                const float2 x3 = *reinterpret_cast<const float2*>(&sx[3][kb + k0 + i]);
                const double w0 = (double)wv[i], w1 = (double)wv[i + 1];
                a0 += (double)x0.x * w0; a0 += (double)x0.y * w1;
                a1 += (double)x1.x * w0; a1 += (double)x1.y * w1;
                a2 += (double)x2.x * w0; a2 += (double)x2.y * w1;
                a3 += (double)x3.x * w0; a3 += (double)x3.y * w1;
            }
        }
        spart[kh][0][col] = a0;
        spart[kh][1][col] = a1;
        spart[kh][2][col] = a2;
        spart[kh][3][col] = a3;
        __syncthreads();

        if (tid < 256) {
#pragma unroll
            for (int j = 0; j < RB; ++j)
                slog[j][tid] = (tid < T_N)
                    ? spart[0][j][tid] + spart[1][j][tid] + (double)br[tid]
                    : -1.0e300;
        }
        __syncthreads();

        if (w < nb) {
            const long tok = toks[w];
            double v[4];
#pragma unroll
            for (int i = 0; i < 4; ++i) v[i] = slog[w][lane + 64 * i];
            double m = fmax(fmax(v[0], v[1]), fmax(v[2], v[3]));
#pragma unroll
            for (int off = 32; off >= 1; off >>= 1)
                m = fmax(m, __shfl_xor(m, off));
            double e[4]; double s = 0.0;
#pragma unroll
            for (int i = 0; i < 4; ++i) {
                e[i] = (v[i] > -1.0e299) ? exp(v[i] - m) : 0.0;
                s += e[i];
            }
#pragma unroll
            for (int off = 32; off >= 1; off >>= 1)
                s += __shfl_xor(s, off);
            const double invZ = 1.0 / s;

            int sel[TOPK];
#pragma unroll 1
            for (int k = 0; k < TOPK; ++k) {
                double bv = -1.0; int bi = 255;
#pragma unroll
                for (int i = 0; i < 4; ++i) {
                    const int t = lane + 64 * i;
                    bool used = false;
                    for (int q = 0; q < k; ++q) used |= (sel[q] == t);
                    if (!used && e[i] > bv) { bv = e[i]; bi = t; }
                }
#pragma unroll
                for (int off = 32; off >= 1; off >>= 1) {
                    const double ov = __shfl_xor(bv, off);
                    const int    oi = __shfl_xor(bi, off);
                    if (ov > bv || (ov == bv && oi < bi)) { bv = ov; bi = oi; }
                }
                sel[k] = bi;
                if (lane == 0) {
                    out_p[tok * TOPK + k] = (float)(bv * invZ);
                    const int* cp = conn + bi * 3;
                    out_n[(tok * TOPK + k) * 3 + 0] = (float)cp[0];
                    out_n[(tok * TOPK + k) * 3 + 1] = (float)cp[1];
                    out_n[(tok * TOPK + k) * 3 + 2] = (float)cp[2];
                }
            }
        }
        __syncthreads();
    }
}

extern "C" void kernel_launch(void* const* d_in, const int* in_sizes, int n_in,
                              void* d_out, int out_size, void* d_ws, size_t ws_size,
                              hipStream_t stream) {
    const float* x    = (const float*)d_in[0];
    const float* Wr   = (const float*)d_in[1];
    const float* br   = (const float*)d_in[2];
    const int*   conn = (const int*)d_in[3];

    float* out_x = (float*)d_out;
    float* out_p = out_x + (size_t)8 * 4096 * 2048;
    float* out_n = out_p + (size_t)8 * 4096 * 8;

    unsigned*       cnt  = (unsigned*)d_ws;
    unsigned*       list = (unsigned*)((char*)d_ws + WS_LIST_OFF);
    unsigned short* wtp  = (unsigned short*)((char*)d_ws + WS_WTP_OFF);

    hipLaunchKernelGGL(prep_pack, dim3(32, 16), dim3(256), 0, stream,
                       Wr, cnt, wtp);
    hipLaunchKernelGGL(router_mfma, dim3(32768 / BM), dim3(512), 0, stream,
                       x, wtp, br, conn, out_x, out_p, out_n, cnt, list);
    hipLaunchKernelGGL(refine_fp64, dim3(1024), dim3(512), 0, stream,
                       x, Wr, br, conn, out_p, out_n, cnt, list);
}

// Round 21
// 291.650 us; speedup vs baseline: 5.5199x; 1.0293x over previous
//
#include <hip/hip_runtime.h>
#include <math.h>

#define D_DIM 2048
#define T_N   245
#define TOPK  8
#define BM    128
#define NC2   64              // 2048 / 32 (BK=32 chunks)

typedef __attribute__((ext_vector_type(8))) __bf16 bf16x8;
typedef __attribute__((ext_vector_type(4))) float  f32x4;

// ws layout (~2.4 MB):
//   [0]        : unsigned counter
//   [256]      : token list, unsigned[32768] (128 KB)
//   [256K]     : wtp packed fragments, bf16 [64 c2][16 fcg][2 hl][64][8] (2 MB)
#define WS_LIST_OFF   256
#define WS_WTP_OFF    (256 * 1024)

// packed strides (bf16 units) — BK=32-chunk-major, chunk = 32 KB contiguous
#define Q_C    16384          // 16*2*64*8
#define Q_FCG  1024           // 2*64*8
#define Q_HL   512            // 64*8

__device__ __forceinline__ unsigned short bf16_rne(float f) {
    unsigned u = __builtin_bit_cast(unsigned, f);
    u += 0x7FFFu + ((u >> 16) & 1u);
    return (unsigned short)(u >> 16);
}
__device__ __forceinline__ float bf16_to_f(unsigned short h) {
    return __builtin_bit_cast(float, (unsigned)h << 16);
}

// async global->LDS, 16 B per lane (1 KB per wave-instr)
__device__ __forceinline__ void gll16(const void* g, void* l) {
    __builtin_amdgcn_global_load_lds(
        (const __attribute__((address_space(1))) void*)g,
        (__attribute__((address_space(3))) void*)l, 16, 0, 0);
}

// split 8 f32 -> hi/lo bf16x8 using v_cvt_pk_bf16_f32 (RNE)
__device__ __forceinline__ void split8(const float4& A, const float4& B,
                                       bf16x8& h8, bf16x8& l8) {
    const float f[8] = {A.x, A.y, A.z, A.w, B.x, B.y, B.z, B.w};
    unsigned hu[4], lu[4];
#pragma unroll
    for (int p = 0; p < 4; ++p) {
        unsigned uh;
        asm("v_cvt_pk_bf16_f32 %0, %1, %2" : "=v"(uh) : "v"(f[2*p]), "v"(f[2*p+1]));
        const float h0 = __builtin_bit_cast(float, uh << 16);
        const float h1 = __builtin_bit_cast(float, uh & 0xffff0000u);
        const float l0 = f[2*p] - h0;
        const float l1 = f[2*p+1] - h1;
        unsigned ul;
        asm("v_cvt_pk_bf16_f32 %0, %1, %2" : "=v"(ul) : "v"(l0), "v"(l1));
        hu[p] = uh; lu[p] = ul;
    }
    uint4 vh = make_uint4(hu[0], hu[1], hu[2], hu[3]);
    uint4 vl = make_uint4(lu[0], lu[1], lu[2], lu[3]);
    h8 = __builtin_bit_cast(bf16x8, vh);
    l8 = __builtin_bit_cast(bf16x8, vl);
}

// ---------------------------------------------------------------------------
// Prep: W [2048][245] fp32 -> wtp, BK=32-chunk-major packed bf16 hi/lo.
// ---------------------------------------------------------------------------
__global__ __launch_bounds__(256)
void prep_pack(const float* __restrict__ W,
               unsigned* __restrict__ cnt,
               unsigned short* __restrict__ wtp)
{
    if (blockIdx.x == 0 && blockIdx.y == 0 && threadIdx.x == 0) *cnt = 0u;

    const int c   = blockIdx.x;          // 0..31
    const int fcg = blockIdx.y;          // 0..15
    const int tid = threadIdx.x;
    const int ks   = tid >> 7;           // 0..1
    const int hl   = (tid >> 6) & 1;     // 0..1
    const int lane = tid & 63;

    const int c2  = c * 2 + ks;          // 0..63
    const int row = fcg * 16 + (lane & 15);
    const int kb  = c2 * 32 + (lane >> 4) * 8;

    unsigned short v[8];
#pragma unroll
    for (int j = 0; j < 8; ++j) {
        const float f = (row < T_N) ? W[(long)(kb + j) * T_N + row] : 0.0f;
        const unsigned short h = bf16_rne(f);
        v[j] = hl ? bf16_rne(f - bf16_to_f(h)) : h;
    }
    const long off = (long)c2 * Q_C + (long)fcg * Q_FCG + hl * Q_HL + lane * 8;
    *reinterpret_cast<uint4*>(wtp + off) = *reinterpret_cast<const uint4*>(v);
}

// ---------------------------------------------------------------------------
// Main router — round-20 structure, BM=128 / 1024 thr / 1 block/CU:
//   B staged once per 128 rows (was per 64) -> per-chunk per-CU VMEM
//   wave-instrs 96 -> 64 (A 16 + B 32 + st 16). Same 16 waves/CU.
//   LDS: A dbuf [2][128][32]f32 32 KB + B dbuf 64 KB = 96 KB; epilogue
//   slog[128][260] = 130 KB (union, 133120 B static < 160 KB).
// ---------------------------------------------------------------------------
__global__ __launch_bounds__(1024, 4)
void router_mfma(const float* __restrict__ x,
                 const unsigned short* __restrict__ wtp,
                 const float* __restrict__ br,
                 const int*   __restrict__ conn,
                 float* __restrict__ out_x,
                 float* __restrict__ out_p,
                 float* __restrict__ out_n,
                 unsigned* __restrict__ cnt,
                 unsigned* __restrict__ list)
{
    __shared__ char smem[133120];        // A dbuf 32 KB | B dbuf 64 KB / slog
    float*          Abuf = (float*)smem;                    // [2][128][32] f32
    unsigned short* Bbuf = (unsigned short*)(smem + 32768); // [2][16384] bf16
    float*          slog = (float*)smem;                    // [128][260] f32

    const int tid  = threadIdx.x;
    const int lane = tid & 63;
    const int wid  = tid >> 6;           // 0..15
    const int wr   = wid >> 2;           // 0..3 (row group of 32)
    const int wc   = wid & 3;            // 0..3 (col quarter)
    const int m16  = lane & 15;
    const int kq   = lane >> 4;          // 0..3
    const long row0 = (long)blockIdx.x * BM;

    f32x4 acc[2][4];
#pragma unroll
    for (int fr = 0; fr < 2; ++fr)
#pragma unroll
        for (int fc = 0; fc < 4; ++fc)
            acc[fr][fc] = (f32x4){0.f, 0.f, 0.f, 0.f};

    // stage A chunk c2: 1 gll/wave (8 rows x 128 B, swizzled source)
    auto stageA = [&](int c2, int b) {
        const int r  = wid * 8 + (lane >> 3);
        const int su = (lane & 7) ^ (r & 7);
        gll16(x + (row0 + r) * (long)D_DIM + c2 * 32 + su * 4,
              Abuf + b * 4096 + wid * 8 * 32);
    };
    // stage B chunk c2: 2 gll/wave (linear 32 KB copy)
    auto stageB = [&](int c2, int b) {
        const unsigned short* src = wtp + (long)c2 * Q_C + wid * 1024;
        unsigned short*       dst = Bbuf + b * 16384 + wid * 1024;
#pragma unroll
        for (int q = 0; q < 2; ++q)
            gll16(src + q * 512 + lane * 8, dst + q * 512);
    };

    // ---- prologue ----
    stageA(0, 0);
    stageB(0, 0);
    __syncthreads();

    for (int c2 = 0; c2 < NC2; ++c2) {
        const int b = c2 & 1;

        // ---- 1. issue next chunk's staging (drained at end barrier) ----
        if (c2 + 1 < NC2) {
            stageA(c2 + 1, b ^ 1);
            stageB(c2 + 1, b ^ 1);
        }

        // ---- 2. x passthrough: full-line stores from LDS-A ----
        {
            const int row = tid >> 3;        // 0..127
            const int lu  = tid & 7;
            float4 v = *reinterpret_cast<const float4*>(
                Abuf + b * 4096 + row * 32 + ((lu ^ (row & 7)) * 4));
            *reinterpret_cast<float4*>(
                out_x + (row0 + row) * (long)D_DIM + c2 * 32 + lu * 4) = v;
        }

        // ---- 3. consume: A/B from LDS, split-bf16 3-pass MFMA ----
        bf16x8 ah[2], al[2];
#pragma unroll
        for (int fr = 0; fr < 2; ++fr) {
            const int row = wr * 32 + fr * 16 + m16;   // 0..127
            const float* Ar = Abuf + b * 4096 + row * 32;
            float4 r0 = *reinterpret_cast<const float4*>(
                Ar + (((kq * 2)     ^ (row & 7)) * 4));
            float4 r1 = *reinterpret_cast<const float4*>(
                Ar + (((kq * 2 + 1) ^ (row & 7)) * 4));
            split8(r0, r1, ah[fr], al[fr]);
        }
#pragma unroll
        for (int fc = 0; fc < 4; ++fc) {
            const unsigned short* Bp = Bbuf + b * 16384
                                       + (wc * 4 + fc) * Q_FCG + lane * 8;
            const bf16x8 bhv = *reinterpret_cast<const bf16x8*>(Bp);
            const bf16x8 blv = *reinterpret_cast<const bf16x8*>(Bp + Q_HL);
#pragma unroll
            for (int fr = 0; fr < 2; ++fr) {
                acc[fr][fc] = __builtin_amdgcn_mfma_f32_16x16x32_bf16(ah[fr], bhv, acc[fr][fc], 0, 0, 0);
                acc[fr][fc] = __builtin_amdgcn_mfma_f32_16x16x32_bf16(al[fr], bhv, acc[fr][fc], 0, 0, 0);
                acc[fr][fc] = __builtin_amdgcn_mfma_f32_16x16x32_bf16(ah[fr], blv, acc[fr][fc], 0, 0, 0);
            }
        }

        // ---- 4. barrier: drains glls(c2+1)+stores, seals buffer swap ----
        __syncthreads();
    }

    // ---- epilogue: logits -> slog (overwrites A/B LDS; barrier above) ----
#pragma unroll
    for (int fr = 0; fr < 2; ++fr)
#pragma unroll
        for (int fc = 0; fc < 4; ++fc)
#pragma unroll
            for (int r = 0; r < 4; ++r) {
                const int rloc = wr * 32 + fr * 16 + kq * 4 + r;   // 0..127
                const int col  = wc * 64 + fc * 16 + m16;
                float v = acc[fr][fc][r];
                v = (col < T_N) ? v + br[col] : -1e30f;
                slog[rloc * 260 + col] = v;
            }
    __syncthreads();

    // ---- per-row softmax + top-8 + gap flag (8 thr/row, logit domain) ----
    {
        const int rloc = tid >> 3;          // 0..127
        const int sub  = tid & 7;           // 0..7
        const long gr  = row0 + rloc;
        const float* base = &slog[rloc * 260];

        float vals[32];
#pragma unroll
        for (int t = 0; t < 32; ++t) vals[t] = base[sub + 8 * t];

        float m = -INFINITY;
#pragma unroll
        for (int t = 0; t < 32; ++t) m = fmaxf(m, vals[t]);
#pragma unroll
        for (int d = 4; d >= 1; d >>= 1) m = fmaxf(m, __shfl_xor(m, d, 8));

        float s = 0.f;
#pragma unroll
        for (int t = 0; t < 32; ++t) s += expf(vals[t] - m);
#pragma unroll
        for (int d = 4; d >= 1; d >>= 1) s += __shfl_xor(s, d, 8);
        const float inv = 1.0f / s;

        unsigned chosen = 0u;
        float prev = INFINITY;
        int flag = 0;
#pragma unroll 1
        for (int k = 0; k < TOPK + 1; ++k) {
            float bv = -INFINITY; int bt = 0;
#pragma unroll
            for (int t = 0; t < 32; ++t)
                if (!((chosen >> t) & 1u) && vals[t] > bv) { bv = vals[t]; bt = t; }
            int bcol = sub + 8 * bt;
#pragma unroll
            for (int d = 4; d >= 1; d >>= 1) {
                const float ov = __shfl_xor(bv, d, 8);
                const int   oc = __shfl_xor(bcol, d, 8);
                if (ov > bv || (ov == bv && oc < bcol)) { bv = ov; bcol = oc; }
            }
            if (prev - bv <= 2e-4f) flag = 1;   // logit gap (INF at k=0 safe)
            prev = bv;
            if (k < TOPK) {
                if ((bcol & 7) == sub) chosen |= 1u << (bcol >> 3);
                if (sub == 0) {
                    out_p[gr * TOPK + k] = expf(bv - m) * inv;
                    const int* cp = conn + bcol * 3;
                    out_n[(gr * TOPK + k) * 3 + 0] = (float)cp[0];
                    out_n[(gr * TOPK + k) * 3 + 1] = (float)cp[1];
                    out_n[(gr * TOPK + k) * 3 + 2] = (float)cp[2];
                }
            }
        }
        if (sub == 0 && flag) {
            unsigned idx = atomicAdd(cnt, 1u);
            if (idx < 32768u) list[idx] = (unsigned)gr;
        }
    }
}

// ---------------------------------------------------------------------------
// Refine: fp64 recompute for flagged tokens (round-7/8 proven: branchless
// clamped loads, MLP 16, 4 tokens/block, wave-parallel top-8).
// ---------------------------------------------------------------------------
#define RB 4
__global__ __launch_bounds__(512)
void refine_fp64(const float* __restrict__ x,
                 const float* __restrict__ W,
                 const float* __restrict__ br,
                 const int*   __restrict__ conn,
                 float* __restrict__ out_p,
                 float* __restrict__ out_n,
                 const unsigned* __restrict__ cnt,
                 const unsigned* __restrict__ list)
{
    __shared__ float  sx[RB][D_DIM];      // 32 KB
    __shared__ double spart[2][RB][256];  // 16 KB
    __shared__ double slog[RB][256];      // 8 KB

    const int tid  = threadIdx.x;
    const int col  = tid & 255;
    const int kh   = tid >> 8;            // 0..1
    const int colc = (col < T_N) ? col : (T_N - 1);   // branchless clamp
    const int lane = tid & 63;
    const int w    = tid >> 6;            // 0..7
    const unsigned count = min(*cnt, 32768u);

    for (unsigned g0 = (unsigned)blockIdx.x * RB; g0 < count;
         g0 += gridDim.x * RB) {
        const int nb = (int)min((unsigned)RB, count - g0);
        long toks[RB];
#pragma unroll
        for (int j = 0; j < RB; ++j) {
            const unsigned idx = (g0 + j < count) ? (g0 + j) : (count - 1);
            toks[j] = (long)list[idx];
            *reinterpret_cast<float4*>(&sx[j][tid * 4]) =
                *reinterpret_cast<const float4*>(x + toks[j] * D_DIM + tid * 4);
        }
        __syncthreads();

        const int kb = kh * 1024;
        double a0 = 0.0, a1 = 0.0, a2 = 0.0, a3 = 0.0;
        for (int k0 = 0; k0 < 1024; k0 += 16) {
            float wv[16];
#pragma unroll
            for (int i = 0; i < 16; ++i)
                wv[i] = W[(long)(kb + k0 + i) * T_N + colc];  // unconditional
#pragma unroll
            for (int i = 0; i < 16; i += 2) {
                const float2 x0 = *reinterpret_cast<const float2*>(&sx[0][kb + k0 + i]);
                const float2 x1 = *reinterpret_cast<const float2*>(&sx[1][kb + k0 + i]);
                const float2 x2 = *reinterpret_cast<const float2*>(&sx[2][kb + k0 + i]);
                const float2 x3 = *reinterpret_cast<const float2*>(&sx[3][kb + k0 + i]);
                const double w0 = (double)wv[i], w1 = (double)wv[i + 1];
                a0 += (double)x0.x * w0; a0 += (double)x0.y * w1;
                a1 += (double)x1.x * w0; a1 += (double)x1.y * w1;
                a2 += (double)x2.x * w0; a2 += (double)x2.y * w1;
                a3 += (double)x3.x * w0; a3 += (double)x3.y * w1;
            }
        }
        spart[kh][0][col] = a0;
        spart[kh][1][col] = a1;
        spart[kh][2][col] = a2;
        spart[kh][3][col] = a3;
        __syncthreads();

        if (tid < 256) {
#pragma unroll
            for (int j = 0; j < RB; ++j)
                slog[j][tid] = (tid < T_N)
                    ? spart[0][j][tid] + spart[1][j][tid] + (double)br[tid]
                    : -1.0e300;
        }
        __syncthreads();

        if (w < nb) {
            const long tok = toks[w];
            double v[4];
#pragma unroll
            for (int i = 0; i < 4; ++i) v[i] = slog[w][lane + 64 * i];
            double m = fmax(fmax(v[0], v[1]), fmax(v[2], v[3]));
#pragma unroll
            for (int off = 32; off >= 1; off >>= 1)
                m = fmax(m, __shfl_xor(m, off));
            double e[4]; double s = 0.0;
#pragma unroll
            for (int i = 0; i < 4; ++i) {
                e[i] = (v[i] > -1.0e299) ? exp(v[i] - m) : 0.0;
                s += e[i];
            }
#pragma unroll
            for (int off = 32; off >= 1; off >>= 1)
                s += __shfl_xor(s, off);
            const double invZ = 1.0 / s;

            int sel[TOPK];
#pragma unroll 1
            for (int k = 0; k < TOPK; ++k) {
                double bv = -1.0; int bi = 255;
#pragma unroll
                for (int i = 0; i < 4; ++i) {
                    const int t = lane + 64 * i;
                    bool used = false;
                    for (int q = 0; q < k; ++q) used |= (sel[q] == t);
                    if (!used && e[i] > bv) { bv = e[i]; bi = t; }
                }
#pragma unroll
                for (int off = 32; off >= 1; off >>= 1) {
                    const double ov = __shfl_xor(bv, off);
                    const int    oi = __shfl_xor(bi, off);
                    if (ov > bv || (ov == bv && oi < bi)) { bv = ov; bi = oi; }
                }
                sel[k] = bi;
                if (lane == 0) {
                    out_p[tok * TOPK + k] = (float)(bv * invZ);
                    const int* cp = conn + bi * 3;
                    out_n[(tok * TOPK + k) * 3 + 0] = (float)cp[0];
                    out_n[(tok * TOPK + k) * 3 + 1] = (float)cp[1];
                    out_n[(tok * TOPK + k) * 3 + 2] = (float)cp[2];
                }
            }
        }
        __syncthreads();
    }
}

extern "C" void kernel_launch(void* const* d_in, const int* in_sizes, int n_in,
                              void* d_out, int out_size, void* d_ws, size_t ws_size,
                              hipStream_t stream) {
    const float* x    = (const float*)d_in[0];
    const float* Wr   = (const float*)d_in[1];
    const float* br   = (const float*)d_in[2];
    const int*   conn = (const int*)d_in[3];

    float* out_x = (float*)d_out;
    float* out_p = out_x + (size_t)8 * 4096 * 2048;
    float* out_n = out_p + (size_t)8 * 4096 * 8;

    unsigned*       cnt  = (unsigned*)d_ws;
    unsigned*       list = (unsigned*)((char*)d_ws + WS_LIST_OFF);
    unsigned short* wtp  = (unsigned short*)((char*)d_ws + WS_WTP_OFF);

    hipLaunchKernelGGL(prep_pack, dim3(32, 16), dim3(256), 0, stream,
                       Wr, cnt, wtp);
    hipLaunchKernelGGL(router_mfma, dim3(32768 / BM), dim3(1024), 0, stream,
                       x, wtp, br, conn, out_x, out_p, out_n, cnt, list);
    hipLaunchKernelGGL(refine_fp64, dim3(1024), dim3(512), 0, stream,
                       x, Wr, br, conn, out_p, out_n, cnt, list);
}

// Round 22
// 267.034 us; speedup vs baseline: 6.0287x; 1.0922x over previous
//
#include <hip/hip_runtime.h>
#include <math.h>

#define D_DIM 2048
#define T_N   245
#define TOPK  8
#define BM    128
#define NC2   64              // 2048 / 32 (BK=32 chunks)

typedef __attribute__((ext_vector_type(8))) __bf16 bf16x8;
typedef __attribute__((ext_vector_type(4))) float  f32x4;

// ws layout (~2.4 MB):
//   [0]        : unsigned counter
//   [256]      : token list, unsigned[32768] (128 KB)
//   [256K]     : wtp packed fragments, bf16 [64 c2][16 fcg][2 hl][64][8] (2 MB)
#define WS_LIST_OFF   256
#define WS_WTP_OFF    (256 * 1024)

// packed strides (bf16 units) — BK=32-chunk-major, chunk = 32 KB contiguous
#define Q_C    16384          // 16*2*64*8
#define Q_FCG  1024           // 2*64*8
#define Q_HL   512            // 64*8

__device__ __forceinline__ unsigned short bf16_rne(float f) {
    unsigned u = __builtin_bit_cast(unsigned, f);
    u += 0x7FFFu + ((u >> 16) & 1u);
    return (unsigned short)(u >> 16);
}
__device__ __forceinline__ float bf16_to_f(unsigned short h) {
    return __builtin_bit_cast(float, (unsigned)h << 16);
}

// async global->LDS, 16 B per lane (1 KB per wave-instr)
__device__ __forceinline__ void gll16(const void* g, void* l) {
    __builtin_amdgcn_global_load_lds(
        (const __attribute__((address_space(1))) void*)g,
        (__attribute__((address_space(3))) void*)l, 16, 0, 0);
}

// split 8 f32 -> hi/lo bf16x8 using v_cvt_pk_bf16_f32 (RNE)
__device__ __forceinline__ void split8(const float4& A, const float4& B,
                                       bf16x8& h8, bf16x8& l8) {
    const float f[8] = {A.x, A.y, A.z, A.w, B.x, B.y, B.z, B.w};
    unsigned hu[4], lu[4];
#pragma unroll
    for (int p = 0; p < 4; ++p) {
        unsigned uh;
        asm("v_cvt_pk_bf16_f32 %0, %1, %2" : "=v"(uh) : "v"(f[2*p]), "v"(f[2*p+1]));
        const float h0 = __builtin_bit_cast(float, uh << 16);
        const float h1 = __builtin_bit_cast(float, uh & 0xffff0000u);
        const float l0 = f[2*p] - h0;
        const float l1 = f[2*p+1] - h1;
        unsigned ul;
        asm("v_cvt_pk_bf16_f32 %0, %1, %2" : "=v"(ul) : "v"(l0), "v"(l1));
        hu[p] = uh; lu[p] = ul;
    }
    uint4 vh = make_uint4(hu[0], hu[1], hu[2], hu[3]);
    uint4 vl = make_uint4(lu[0], lu[1], lu[2], lu[3]);
    h8 = __builtin_bit_cast(bf16x8, vh);
    l8 = __builtin_bit_cast(bf16x8, vl);
}

// ---------------------------------------------------------------------------
// Prep: W [2048][245] fp32 -> wtp, BK=32-chunk-major packed bf16 hi/lo.
// ---------------------------------------------------------------------------
__global__ __launch_bounds__(256)
void prep_pack(const float* __restrict__ W,
               unsigned* __restrict__ cnt,
               unsigned short* __restrict__ wtp)
{
    if (blockIdx.x == 0 && blockIdx.y == 0 && threadIdx.x == 0) *cnt = 0u;

    const int c   = blockIdx.x;          // 0..31
    const int fcg = blockIdx.y;          // 0..15
    const int tid = threadIdx.x;
    const int ks   = tid >> 7;           // 0..1
    const int hl   = (tid >> 6) & 1;     // 0..1
    const int lane = tid & 63;

    const int c2  = c * 2 + ks;          // 0..63
    const int row = fcg * 16 + (lane & 15);
    const int kb  = c2 * 32 + (lane >> 4) * 8;

    unsigned short v[8];
#pragma unroll
    for (int j = 0; j < 8; ++j) {
        const float f = (row < T_N) ? W[(long)(kb + j) * T_N + row] : 0.0f;
        const unsigned short h = bf16_rne(f);
        v[j] = hl ? bf16_rne(f - bf16_to_f(h)) : h;
    }
    const long off = (long)c2 * Q_C + (long)fcg * Q_FCG + hl * Q_HL + lane * 8;
    *reinterpret_cast<uint4*>(wtp + off) = *reinterpret_cast<const uint4*>(v);
}

// ---------------------------------------------------------------------------
// Main router — round-21 structure + counted-vmcnt barrier:
//   Per wave per chunk the VMEM issue order is pinned [A-gll, B-gll x2,
//   store]; compute is LDS/VALU/MFMA only. End-of-chunk barrier =
//   s_waitcnt vmcnt(1) + raw s_barrier: all glls (buf c2+1) retired, the
//   store (unique youngest) stays in flight and drains under the next
//   chunk. At 1 block/CU there is no co-resident block to hide a vmcnt(0)
//   drain — this removes ~900-cyc store-ack from every chunk's critical
//   path (round 9's null was measured at 2 blocks/CU where it was hidden).
// ---------------------------------------------------------------------------
__global__ __launch_bounds__(1024, 4)
void router_mfma(const float* __restrict__ x,
                 const unsigned short* __restrict__ wtp,
                 const float* __restrict__ br,
                 const int*   __restrict__ conn,
                 float* __restrict__ out_x,
                 float* __restrict__ out_p,
                 float* __restrict__ out_n,
                 unsigned* __restrict__ cnt,
                 unsigned* __restrict__ list)
{
    __shared__ char smem[133120];        // A dbuf 32 KB | B dbuf 64 KB / slog
    float*          Abuf = (float*)smem;                    // [2][128][32] f32
    unsigned short* Bbuf = (unsigned short*)(smem + 32768); // [2][16384] bf16
    float*          slog = (float*)smem;                    // [128][260] f32

    const int tid  = threadIdx.x;
    const int lane = tid & 63;
    const int wid  = tid >> 6;           // 0..15
    const int wr   = wid >> 2;           // 0..3 (row group of 32)
    const int wc   = wid & 3;            // 0..3 (col quarter)
    const int m16  = lane & 15;
    const int kq   = lane >> 4;          // 0..3
    const long row0 = (long)blockIdx.x * BM;

    f32x4 acc[2][4];
#pragma unroll
    for (int fr = 0; fr < 2; ++fr)
#pragma unroll
        for (int fc = 0; fc < 4; ++fc)
            acc[fr][fc] = (f32x4){0.f, 0.f, 0.f, 0.f};

    // stage A chunk c2: 1 gll/wave (8 rows x 128 B, swizzled source)
    auto stageA = [&](int c2, int b) {
        const int r  = wid * 8 + (lane >> 3);
        const int su = (lane & 7) ^ (r & 7);
        gll16(x + (row0 + r) * (long)D_DIM + c2 * 32 + su * 4,
              Abuf + b * 4096 + wid * 8 * 32);
    };
    // stage B chunk c2: 2 gll/wave (linear 32 KB copy)
    auto stageB = [&](int c2, int b) {
        const unsigned short* src = wtp + (long)c2 * Q_C + wid * 1024;
        unsigned short*       dst = Bbuf + b * 16384 + wid * 1024;
#pragma unroll
        for (int q = 0; q < 2; ++q)
            gll16(src + q * 512 + lane * 8, dst + q * 512);
    };

    // ---- prologue ----
    stageA(0, 0);
    stageB(0, 0);
    __syncthreads();

    for (int c2 = 0; c2 < NC2; ++c2) {
        const int b = c2 & 1;

        // ---- 1. issue next chunk's staging (retired at end-of-chunk wait) ----
        if (c2 + 1 < NC2) {
            stageA(c2 + 1, b ^ 1);
            stageB(c2 + 1, b ^ 1);
        }
        __builtin_amdgcn_sched_barrier(0);   // glls strictly older than store

        // ---- 2. x passthrough: full-line store from LDS-A (youngest VMEM) ----
        {
            const int row = tid >> 3;        // 0..127
            const int lu  = tid & 7;
            float4 v = *reinterpret_cast<const float4*>(
                Abuf + b * 4096 + row * 32 + ((lu ^ (row & 7)) * 4));
            *reinterpret_cast<float4*>(
                out_x + (row0 + row) * (long)D_DIM + c2 * 32 + lu * 4) = v;
        }
        __builtin_amdgcn_sched_barrier(0);   // no VMEM below this point

        // ---- 3. consume: A/B from LDS, split-bf16 3-pass MFMA ----
        bf16x8 ah[2], al[2];
#pragma unroll
        for (int fr = 0; fr < 2; ++fr) {
            const int row = wr * 32 + fr * 16 + m16;   // 0..127
            const float* Ar = Abuf + b * 4096 + row * 32;
            float4 r0 = *reinterpret_cast<const float4*>(
                Ar + (((kq * 2)     ^ (row & 7)) * 4));
            float4 r1 = *reinterpret_cast<const float4*>(
                Ar + (((kq * 2 + 1) ^ (row & 7)) * 4));
            split8(r0, r1, ah[fr], al[fr]);
        }
#pragma unroll
        for (int fc = 0; fc < 4; ++fc) {
            const unsigned short* Bp = Bbuf + b * 16384
                                       + (wc * 4 + fc) * Q_FCG + lane * 8;
            const bf16x8 bhv = *reinterpret_cast<const bf16x8*>(Bp);
            const bf16x8 blv = *reinterpret_cast<const bf16x8*>(Bp + Q_HL);
#pragma unroll
            for (int fr = 0; fr < 2; ++fr) {
                acc[fr][fc] = __builtin_amdgcn_mfma_f32_16x16x32_bf16(ah[fr], bhv, acc[fr][fc], 0, 0, 0);
                acc[fr][fc] = __builtin_amdgcn_mfma_f32_16x16x32_bf16(al[fr], bhv, acc[fr][fc], 0, 0, 0);
                acc[fr][fc] = __builtin_amdgcn_mfma_f32_16x16x32_bf16(ah[fr], blv, acc[fr][fc], 0, 0, 0);
            }
        }

        // ---- 4. counted barrier: glls(c2+1) retired; store stays in flight ----
        __builtin_amdgcn_sched_barrier(0);
        asm volatile("s_waitcnt vmcnt(1)" ::: "memory");
        __builtin_amdgcn_s_barrier();
        __builtin_amdgcn_sched_barrier(0);
    }

    // ---- epilogue: logits -> slog (LDS reuse safe: all LDS ops sealed by
    //      the final barrier; in-flight global stores don't touch LDS) ----
#pragma unroll
    for (int fr = 0; fr < 2; ++fr)
#pragma unroll
        for (int fc = 0; fc < 4; ++fc)
#pragma unroll
            for (int r = 0; r < 4; ++r) {
                const int rloc = wr * 32 + fr * 16 + kq * 4 + r;   // 0..127
                const int col  = wc * 64 + fc * 16 + m16;
                float v = acc[fr][fc][r];
                v = (col < T_N) ? v + br[col] : -1e30f;
                slog[rloc * 260 + col] = v;
            }
    __syncthreads();

    // ---- per-row softmax + top-8 + gap flag (8 thr/row, logit domain) ----
    {
        const int rloc = tid >> 3;          // 0..127
        const int sub  = tid & 7;           // 0..7
        const long gr  = row0 + rloc;
        const float* base = &slog[rloc * 260];

        float vals[32];
#pragma unroll
        for (int t = 0; t < 32; ++t) vals[t] = base[sub + 8 * t];

        float m = -INFINITY;
#pragma unroll
        for (int t = 0; t < 32; ++t) m = fmaxf(m, vals[t]);
#pragma unroll
        for (int d = 4; d >= 1; d >>= 1) m = fmaxf(m, __shfl_xor(m, d, 8));

        float s = 0.f;
#pragma unroll
        for (int t = 0; t < 32; ++t) s += expf(vals[t] - m);
#pragma unroll
        for (int d = 4; d >= 1; d >>= 1) s += __shfl_xor(s, d, 8);
        const float inv = 1.0f / s;

        unsigned chosen = 0u;
        float prev = INFINITY;
        int flag = 0;
#pragma unroll 1
        for (int k = 0; k < TOPK + 1; ++k) {
            float bv = -INFINITY; int bt = 0;
#pragma unroll
            for (int t = 0; t < 32; ++t)
                if (!((chosen >> t) & 1u) && vals[t] > bv) { bv = vals[t]; bt = t; }
            int bcol = sub + 8 * bt;
#pragma unroll
            for (int d = 4; d >= 1; d >>= 1) {
                const float ov = __shfl_xor(bv, d, 8);
                const int   oc = __shfl_xor(bcol, d, 8);
                if (ov > bv || (ov == bv && oc < bcol)) { bv = ov; bcol = oc; }
            }
            if (prev - bv <= 2e-4f) flag = 1;   // logit gap (INF at k=0 safe)
            prev = bv;
            if (k < TOPK) {
                if ((bcol & 7) == sub) chosen |= 1u << (bcol >> 3);
                if (sub == 0) {
                    out_p[gr * TOPK + k] = expf(bv - m) * inv;
                    const int* cp = conn + bcol * 3;
                    out_n[(gr * TOPK + k) * 3 + 0] = (float)cp[0];
                    out_n[(gr * TOPK + k) * 3 + 1] = (float)cp[1];
                    out_n[(gr * TOPK + k) * 3 + 2] = (float)cp[2];
                }
            }
        }
        if (sub == 0 && flag) {
            unsigned idx = atomicAdd(cnt, 1u);
            if (idx < 32768u) list[idx] = (unsigned)gr;
        }
    }
}

// ---------------------------------------------------------------------------
// Refine: fp64 recompute for flagged tokens (round-7/8 proven: branchless
// clamped loads, MLP 16, 4 tokens/block, wave-parallel top-8).
// ---------------------------------------------------------------------------
#define RB 4
__global__ __launch_bounds__(512)
void refine_fp64(const float* __restrict__ x,
                 const float* __restrict__ W,
                 const float* __restrict__ br,
                 const int*   __restrict__ conn,
                 float* __restrict__ out_p,
                 float* __restrict__ out_n,
                 const unsigned* __restrict__ cnt,
                 const unsigned* __restrict__ list)
{
    __shared__ float  sx[RB][D_DIM];      // 32 KB
    __shared__ double spart[2][RB][256];  // 16 KB
    __shared__ double slog[RB][256];      // 8 KB

    const int tid  = threadIdx.x;
    const int col  = tid & 255;
    const int kh   = tid >> 8;            // 0..1
    const int colc = (col < T_N) ? col : (T_N - 1);   // branchless clamp
    const int lane = tid & 63;
    const int w    = tid >> 6;            // 0..7
    const unsigned count = min(*cnt, 32768u);

    for (unsigned g0 = (unsigned)blockIdx.x * RB; g0 < count;
         g0 += gridDim.x * RB) {
        const int nb = (int)min((unsigned)RB, count - g0);
        long toks[RB];
#pragma unroll
        for (int j = 0; j < RB; ++j) {
            const unsigned idx = (g0 + j < count) ? (g0 + j) : (count - 1);
            toks[j] = (long)list[idx];
            *reinterpret_cast<float4*>(&sx[j][tid * 4]) =
                *reinterpret_cast<const float4*>(x + toks[j] * D_DIM + tid * 4);
        }
        __syncthreads();

        const int kb = kh * 1024;
        double a0 = 0.0, a1 = 0.0, a2 = 0.0, a3 = 0.0;
        for (int k0 = 0; k0 < 1024; k0 += 16) {
            float wv[16];
#pragma unroll
            for (int i = 0; i < 16; ++i)
                wv[i] = W[(long)(kb + k0 + i) * T_N + colc];  // unconditional
#pragma unroll
            for (int i = 0; i < 16; i += 2) {
                const float2 x0 = *reinterpret_cast<const float2*>(&sx[0][kb + k0 + i]);
                const float2 x1 = *reinterpret_cast<const float2*>(&sx[1][kb + k0 + i]);
                const float2 x2 = *reinterpret_cast<const float2*>(&sx[2][kb + k0 + i]);
                const float2 x3 = *reinterpret_cast<const float2*>(&sx[3][kb + k0 + i]);
                const double w0 = (double)wv[i], w1 = (double)wv[i + 1];
                a0 += (double)x0.x * w0; a0 += (double)x0.y * w1;
                a1 += (double)x1.x * w0; a1 += (double)x1.y * w1;
                a2 += (double)x2.x * w0; a2 += (double)x2.y * w1;
                a3 += (double)x3.x * w0; a3 += (double)x3.y * w1;
            }
        }
        spart[kh][0][col] = a0;
        spart[kh][1][col] = a1;
        spart[kh][2][col] = a2;
        spart[kh][3][col] = a3;
        __syncthreads();

        if (tid < 256) {
#pragma unroll
            for (int j = 0; j < RB; ++j)
                slog[j][tid] = (tid < T_N)
                    ? spart[0][j][tid] + spart[1][j][tid] + (double)br[tid]
                    : -1.0e300;
        }
        __syncthreads();

        if (w < nb) {
            const long tok = toks[w];
            double v[4];
#pragma unroll
            for (int i = 0; i < 4; ++i) v[i] = slog[w][lane + 64 * i];
            double m = fmax(fmax(v[0], v[1]), fmax(v[2], v[3]));
#pragma unroll
            for (int off = 32; off >= 1; off >>= 1)
                m = fmax(m, __shfl_xor(m, off));
            double e[4]; double s = 0.0;
#pragma unroll
            for (int i = 0; i < 4; ++i) {
                e[i] = (v[i] > -1.0e299) ? exp(v[i] - m) : 0.0;
                s += e[i];
            }
#pragma unroll
            for (int off = 32; off >= 1; off >>= 1)
                s += __shfl_xor(s, off);
            const double invZ = 1.0 / s;

            int sel[TOPK];
#pragma unroll 1
            for (int k = 0; k < TOPK; ++k) {
                double bv = -1.0; int bi = 255;
#pragma unroll
                for (int i = 0; i < 4; ++i) {
                    const int t = lane + 64 * i;
                    bool used = false;
                    for (int q = 0; q < k; ++q) used |= (sel[q] == t);
                    if (!used && e[i] > bv) { bv = e[i]; bi = t; }
                }
#pragma unroll
                for (int off = 32; off >= 1; off >>= 1) {
                    const double ov = __shfl_xor(bv, off);
                    const int    oi = __shfl_xor(bi, off);
                    if (ov > bv || (ov == bv && oi < bi)) { bv = ov; bi = oi; }
                }
                sel[k] = bi;
                if (lane == 0) {
                    out_p[tok * TOPK + k] = (float)(bv * invZ);
                    const int* cp = conn + bi * 3;
                    out_n[(tok * TOPK + k) * 3 + 0] = (float)cp[0];
                    out_n[(tok * TOPK + k) * 3 + 1] = (float)cp[1];
                    out_n[(tok * TOPK + k) * 3 + 2] = (float)cp[2];
                }
            }
        }
        __syncthreads();
    }
}

extern "C" void kernel_launch(void* const* d_in, const int* in_sizes, int n_in,
                              void* d_out, int out_size, void* d_ws, size_t ws_size,
                              hipStream_t stream) {
    const float* x    = (const float*)d_in[0];
    const float* Wr   = (const float*)d_in[1];
    const float* br   = (const float*)d_in[2];
    const int*   conn = (const int*)d_in[3];

    float* out_x = (float*)d_out;
    float* out_p = out_x + (size_t)8 * 4096 * 2048;
    float* out_n = out_p + (size_t)8 * 4096 * 8;

    unsigned*       cnt  = (unsigned*)d_ws;
    unsigned*       list = (unsigned*)((char*)d_ws + WS_LIST_OFF);
    unsigned short* wtp  = (unsigned short*)((char*)d_ws + WS_WTP_OFF);

    hipLaunchKernelGGL(prep_pack, dim3(32, 16), dim3(256), 0, stream,
                       Wr, cnt, wtp);
    hipLaunchKernelGGL(router_mfma, dim3(32768 / BM), dim3(1024), 0, stream,
                       x, wtp, br, conn, out_x, out_p, out_n, cnt, list);
    hipLaunchKernelGGL(refine_fp64, dim3(2048), dim3(512), 0, stream,
                       x, Wr, br, conn, out_p, out_n, cnt, list);
}